// Round 11
// baseline (491.523 us; speedup 1.0000x reference)
//
#include <hip/hip_runtime.h>
#include <hip/hip_bf16.h>
#include <math.h>

#define SCL 0.125f

typedef float f32x4 __attribute__((ext_vector_type(4)));
typedef short bf16x8 __attribute__((ext_vector_type(8)));   // 8 bf16 in 4 VGPRs
#define MFMA16(a, b, c) __builtin_amdgcn_mfma_f32_16x16x32_bf16((a), (b), (c), 0, 0, 0)

// f32 -> bf16 round-to-nearest-even
__device__ __forceinline__ unsigned short f2bf(float f) {
    unsigned int u = __builtin_bit_cast(unsigned int, f);
    u = (u + 0x7FFFu + ((u >> 16) & 1u)) >> 16;
    return (unsigned short)u;
}

__device__ __forceinline__ float gelu_exact(float v) {
    return 0.5f * v * (1.f + erff(v * 0.70710678118654752f));
}

// ---------------------------------------------------------------------------
// Fused LayerNorm: row 0..25 = cls tokens (g1/b1, fp32 -> n1),
// row 26..5121 = image tokens (g2/b2, bf16 -> n2_bf; first 3136 xs, rest anchors).
// One wave per row.
// ---------------------------------------------------------------------------
__global__ void ln_all(const float* __restrict__ x, float* __restrict__ n1,
                       unsigned short* __restrict__ n2_bf,
                       const float* __restrict__ g1, const float* __restrict__ b1,
                       const float* __restrict__ g2, const float* __restrict__ b2) {
    const int row = blockIdx.x;
    const int lane = threadIdx.x;
    const float* src;
    const float *g, *bt;
    if (row < 26) {
        src = x + (size_t)row * (197 * 384);
        g = g1; bt = b1;
    } else {
        const int rr = row - 26;
        if (rr < 3136) { int b = rr / 196, n = rr % 196; src = x + (size_t)(b * 197 + 1 + n) * 384; }
        else { int r2 = rr - 3136; int b = r2 / 196, n = r2 % 196; src = x + (size_t)((16 + b) * 197 + 1 + n) * 384; }
        g = g2; bt = b2;
    }

    float v[6];
    float s = 0.f, s2 = 0.f;
#pragma unroll
    for (int j = 0; j < 6; j++) {
        v[j] = src[lane + j * 64];
        s += v[j];
        s2 += v[j] * v[j];
    }
#pragma unroll
    for (int o = 32; o; o >>= 1) {
        s  += __shfl_xor(s, o);
        s2 += __shfl_xor(s2, o);
    }
    const float mu = s * (1.f / 384.f);
    const float var = s2 * (1.f / 384.f) - mu * mu;
    const float rs = 1.f / sqrtf(var + 1e-5f);
#pragma unroll
    for (int j = 0; j < 6; j++) {
        const int c = lane + j * 64;
        const float r = (v[j] - mu) * rs * g[c] + bt[c];
        if (row < 26) n1[(size_t)row * 384 + c] = r;
        else          n2_bf[(size_t)(row - 26) * 384 + c] = f2bf(r);
    }
}

// ---------------------------------------------------------------------------
// LN3 (plain contiguous rows, bf16 out) — used for hdn.
// ---------------------------------------------------------------------------
__global__ void ln3_kernel(const float* __restrict__ x, unsigned short* __restrict__ outp,
                           const float* __restrict__ g, const float* __restrict__ bt) {
    const int row = blockIdx.x;
    const int lane = threadIdx.x;
    const float* src = x + (size_t)row * 384;
    float v[6];
    float s = 0.f, s2 = 0.f;
#pragma unroll
    for (int j = 0; j < 6; j++) {
        v[j] = src[lane + j * 64];
        s += v[j];
        s2 += v[j] * v[j];
    }
#pragma unroll
    for (int o = 32; o; o >>= 1) {
        s  += __shfl_xor(s, o);
        s2 += __shfl_xor(s2, o);
    }
    const float mu = s * (1.f / 384.f);
    const float var = s2 * (1.f / 384.f) - mu * mu;
    const float rs = 1.f / sqrtf(var + 1e-5f);
#pragma unroll
    for (int j = 0; j < 6; j++) {
        const int c = lane + j * 64;
        outp[(size_t)row * 384 + c] = f2bf((v[j] - mu) * rs * g[c] + bt[c]);
    }
}

// ---------------------------------------------------------------------------
// cls-path GEMM, latency-optimized (round 6: 140 -> ~5 µs class).
// ---------------------------------------------------------------------------
template <int M>
__global__ void gemm_cls(const float* __restrict__ A, const float* __restrict__ B,
                         const float* __restrict__ bias, float* __restrict__ C,
                         int N, int ldc) {
    __shared__ float sA[M * 384];
    __shared__ float red[4][M][64];
    const int t = threadIdx.x;
    const int tc = t & 63, ks = t >> 6;
    const int n = blockIdx.x * 64 + tc;
    for (int e = t; e < M * 384; e += 256) sA[e] = A[e];
    __syncthreads();
    float acc[M];
#pragma unroll
    for (int m = 0; m < M; m++) acc[m] = 0.f;
    const int k0 = ks * 96;
#pragma unroll 4
    for (int k = k0; k < k0 + 96; k++) {
        const float bv = B[(size_t)k * N + n];
#pragma unroll
        for (int m = 0; m < M; m++) acc[m] += sA[m * 384 + k] * bv;
    }
#pragma unroll
    for (int m = 0; m < M; m++) red[ks][m][tc] = acc[m];
    __syncthreads();
    if (ks == 0) {
#pragma unroll
        for (int m = 0; m < M; m++) {
            float s = red[0][m][tc] + red[1][m][tc] + red[2][m][tc] + red[3][m][tc];
            if (bias) s += bias[n];
            C[(size_t)m * ldc + n] = s;
        }
    }
}

// ---------------------------------------------------------------------------
// cls attention (verified)
// ---------------------------------------------------------------------------
__global__ void attn_cls_kernel(const float* __restrict__ qv, const float* __restrict__ kcls,
                                float* __restrict__ aflat, float* __restrict__ cls_pre) {
    const int b = blockIdx.x;
    const int t = threadIdx.x;  // 64
    __shared__ float kb[384];
    __shared__ float pl[60];
#pragma unroll
    for (int j = 0; j < 6; j++) kb[t + j * 64] = kcls[b * 384 + t + j * 64];
    __syncthreads();
    if (t < 60) {
        const int n = t / 6, h = t % 6;
        float acc = 0.f;
        for (int d = 0; d < 64; d++) acc += qv[n * 768 + h * 64 + d] * kb[h * 64 + d];
        pl[t] = acc * SCL;
    }
    __syncthreads();
    if (t < 6) {
        float m = -1e30f;
        for (int n = 0; n < 10; n++) m = fmaxf(m, pl[n * 6 + t]);
        float p[10], sum = 0.f;
        for (int n = 0; n < 10; n++) { p[n] = expf(pl[n * 6 + t] - m); sum += p[n]; }
        const float inv = 1.f / sum;
        for (int n = 0; n < 10; n++) {
            const float pr = p[n] * inv;
            pl[n * 6 + t] = pr;
            aflat[b * 60 + n * 6 + t] = pr;   // reference flat (n,h) order
        }
    }
    __syncthreads();
#pragma unroll
    for (int j = 0; j < 6; j++) {
        const int c = t + j * 64;
        const int h = c >> 6;
        float acc = 0.f;
        for (int n = 0; n < 10; n++) acc += pl[n * 6 + h] * qv[n * 768 + 384 + c];
        cls_pre[b * 384 + c] = acc;
    }
}

// ---------------------------------------------------------------------------
// ALL weight transpose-casts in ONE launch (was 4 launches).
// blockIdx.x ranges: [0,108) Wqk|Wqk2|Wv -> Wx_t (3x 6x6 tiles);
// [108,144) Wr (6x6); [144,288) W1 384x1536 (24x6); [288,432) W2 1536x384 (6x24).
// Per tile: Wt[n][k] = bf16(W[k][n]), 64x64.
// ---------------------------------------------------------------------------
__global__ void wcast_all(const float* __restrict__ Wqk, const float* __restrict__ Wqk2,
                          const float* __restrict__ Wv, const float* __restrict__ Wr,
                          const float* __restrict__ W1, const float* __restrict__ W2,
                          unsigned short* __restrict__ Wx_t, unsigned short* __restrict__ Wr_t,
                          unsigned short* __restrict__ W1_t, unsigned short* __restrict__ W2_t) {
    const int bid = blockIdx.x;
    const float* W; unsigned short* dst; int K, N, nx, ky;
    if (bid < 108) {
        const int z = bid / 36, rem = bid % 36;
        W = (z == 0) ? Wqk : (z == 1 ? Wqk2 : Wv);
        dst = Wx_t + (size_t)z * 384 * 384;
        K = 384; N = 384; nx = rem % 6; ky = rem / 6;
    } else if (bid < 144) {
        const int rem = bid - 108;
        W = Wr; dst = Wr_t; K = 384; N = 384; nx = rem % 6; ky = rem / 6;
    } else if (bid < 288) {
        const int rem = bid - 144;
        W = W1; dst = W1_t; K = 384; N = 1536; nx = rem % 24; ky = rem / 24;
    } else {
        const int rem = bid - 288;
        W = W2; dst = W2_t; K = 1536; N = 384; nx = rem % 6; ky = rem / 6;
    }
    const int n0 = nx * 64, k0 = ky * 64;
    __shared__ unsigned short sT[64][72];
    const int t = threadIdx.x;
    for (int e = t; e < 4096; e += 256) {
        const int k = e >> 6, n = e & 63;
        sT[n][k] = f2bf(W[(size_t)(k0 + k) * N + n0 + n]);
    }
    __syncthreads();
    for (int e = t; e < 512; e += 256) {
        const int n = e >> 3, ch = e & 7;
        *(uint4*)&dst[(size_t)(n0 + n) * K + k0 + ch * 8] = *(uint4*)&sT[n][ch * 8];
    }
}

// ---------------------------------------------------------------------------
// bf16 MFMA GEMM: C = epilogue(A @ Bt^T). A [M][K] bf16, Bt [N][K] bf16.
// BM=64, BN=128, BK=64, 256 threads.
// EPI: 0 bf16-out plain; 1 fp32 +bias +res REMAP (row->row+row/196+1);
//      2 bf16 +bias +GELU; 3 fp32 +bias +res.
// ---------------------------------------------------------------------------
template <int EPI>
__launch_bounds__(256)
__global__ void gemm_mfma(const unsigned short* __restrict__ A,
                          const unsigned short* __restrict__ Bt,
                          const float* __restrict__ bias, const float* __restrict__ res,
                          void* __restrict__ Cout, int M, int N, int K) {
    const int m0 = blockIdx.y * 64, n0 = blockIdx.x * 128;
    const int t = threadIdx.x;
    const int w = t >> 6, l = t & 63;
    const int lr = l & 15, lk = l >> 4;
    const int wr = w >> 1, wc = w & 1;

    __shared__ unsigned short sA[64][72];
    __shared__ unsigned short sB[128][72];

    f32x4 acc[2][4];
#pragma unroll
    for (int mi = 0; mi < 2; mi++)
#pragma unroll
        for (int nj = 0; nj < 4; nj++) acc[mi][nj] = (f32x4){0.f, 0.f, 0.f, 0.f};

    for (int k0 = 0; k0 < K; k0 += 64) {
        for (int e = t; e < 512; e += 256) {
            const int r = e >> 3, ch = e & 7;
            uint4 v = make_uint4(0, 0, 0, 0);
            const int row = m0 + r;
            if (row < M) v = *(const uint4*)(A + (size_t)row * K + k0 + ch * 8);
            *(uint4*)&sA[r][ch * 8] = v;
        }
        for (int e = t; e < 1024; e += 256) {
            const int r = e >> 3, ch = e & 7;
            *(uint4*)&sB[r][ch * 8] = *(const uint4*)(Bt + (size_t)(n0 + r) * K + k0 + ch * 8);
        }
        __syncthreads();
#pragma unroll
        for (int kc = 0; kc < 2; kc++) {
            bf16x8 af[2], bfr[4];
#pragma unroll
            for (int mi = 0; mi < 2; mi++)
                af[mi] = *(const bf16x8*)&sA[wr * 32 + mi * 16 + lr][kc * 32 + lk * 8];
#pragma unroll
            for (int nj = 0; nj < 4; nj++)
                bfr[nj] = *(const bf16x8*)&sB[wc * 64 + nj * 16 + lr][kc * 32 + lk * 8];
#pragma unroll
            for (int mi = 0; mi < 2; mi++)
#pragma unroll
                for (int nj = 0; nj < 4; nj++)
                    acc[mi][nj] = MFMA16(af[mi], bfr[nj], acc[mi][nj]);
        }
        __syncthreads();
    }

#pragma unroll
    for (int mi = 0; mi < 2; mi++)
#pragma unroll
        for (int nj = 0; nj < 4; nj++) {
            const int col = n0 + wc * 64 + nj * 16 + lr;
#pragma unroll
            for (int i = 0; i < 4; i++) {
                const int row = m0 + wr * 32 + mi * 16 + lk * 4 + i;
                if (row >= M) continue;
                float v = acc[mi][nj][i];
                if (EPI == 0) {
                    ((unsigned short*)Cout)[(size_t)row * N + col] = f2bf(v);
                } else if (EPI == 1) {
                    const int crow = row + row / 196 + 1;
                    v += bias[col] + res[(size_t)crow * N + col];
                    ((float*)Cout)[(size_t)crow * N + col] = v;
                } else if (EPI == 2) {
                    ((unsigned short*)Cout)[(size_t)row * N + col] = f2bf(gelu_exact(v + bias[col]));
                } else {
                    v += bias[col] + res[(size_t)row * N + col];
                    ((float*)Cout)[(size_t)row * N + col] = v;
                }
            }
        }
}

// ===========================================================================
// MFMA chain, stage A — v2 (round 9 verified: 2 blocks/CU, fused S->R->Z).
// ===========================================================================
__global__ __launch_bounds__(256, 2)
void rz_kernel(const unsigned short* __restrict__ Q2b, const unsigned short* __restrict__ K2b,
               const unsigned short* __restrict__ VRb, unsigned short* __restrict__ Zt,
               int sq, int sk, int sv) {
    const int c = blockIdx.x, h = blockIdx.y, b = blockIdx.z;
    const int t = threadIdx.x;
    const int w = t >> 6, l = t & 63;
    const int lr = l & 15, lk = l >> 4;

    __shared__ unsigned short sVT[64 * 232];        // vr^T [d][k], 29,696 B
    __shared__ unsigned short sR[4 * 16 * 232];     // per-wave R tile, 29,696 B
    unsigned short* sRw = sR + w * (16 * 232);

    const unsigned short* vrsrc = VRb + (size_t)(b * 196) * sv + h * 64;
    for (int e = t; e < 196 * 8; e += 256) {
        const int kk = e >> 3, ch = e & 7;
        uint4 v = *(const uint4*)(vrsrc + (size_t)kk * sv + ch * 8);
        unsigned short vs[8]; *(uint4*)vs = v;
#pragma unroll
        for (int j = 0; j < 8; j++) sVT[(ch * 8 + j) * 232 + kk] = vs[j];
    }
    for (int e = t; e < 64 * 36; e += 256) sVT[(e / 36) * 232 + 196 + (e % 36)] = 0;
    for (int e = l; e < 16 * 24; e += 64) sRw[(e / 24) * 232 + 208 + (e % 24)] = 0;

    bf16x8 qf0[13], qf1[13];
    const unsigned short* q2src = Q2b + (size_t)(b * 196) * sq + h * 64;
#pragma unroll
    for (int kt = 0; kt < 13; kt++) {
        const int r = kt * 16 + lr;
        if (r < 196) {
            const unsigned short* p = q2src + (size_t)r * sq;
            qf0[kt] = *(const bf16x8*)(p + lk * 8);
            qf1[kt] = *(const bf16x8*)(p + 32 + lk * 8);
        } else {
            qf0[kt] = (bf16x8){0, 0, 0, 0, 0, 0, 0, 0};
            qf1[kt] = (bf16x8){0, 0, 0, 0, 0, 0, 0, 0};
        }
    }
    __syncthreads();

    const unsigned short* k2src = K2b + (size_t)(c * 196) * sk + h * 64;
    unsigned short* zdst = Zt + ((((size_t)(b * 6 + h)) * 10 + c) * 64) * 208;

    for (int mt = w; mt < 13; mt += 4) {
        bf16x8 a0, a1;
        const int ar = mt * 16 + lr;
        if (ar < 196) {
            const unsigned short* p = k2src + (size_t)ar * sk;
            a0 = *(const bf16x8*)(p + lk * 8);
            a1 = *(const bf16x8*)(p + 32 + lk * 8);
        } else {
            a0 = (bf16x8){0, 0, 0, 0, 0, 0, 0, 0};
            a1 = (bf16x8){0, 0, 0, 0, 0, 0, 0, 0};
        }
#pragma unroll
        for (int kt = 0; kt < 13; kt++) {
            f32x4 acc = {0.f, 0.f, 0.f, 0.f};
            acc = MFMA16(a0, qf0[kt], acc);
            acc = MFMA16(a1, qf1[kt], acc);
#pragma unroll
            for (int i = 0; i < 4; i++)
                sRw[(lk * 4 + i) * 232 + kt * 16 + lr] = f2bf(fmaxf(0.f, SCL * acc[i]));
        }
#pragma unroll
        for (int dt = 0; dt < 4; dt++) {
            f32x4 acc = {0.f, 0.f, 0.f, 0.f};
#pragma unroll
            for (int kc = 0; kc < 7; kc++) {
                bf16x8 a  = *(const bf16x8*)&sRw[lr * 232 + kc * 32 + lk * 8];
                bf16x8 bb = *(const bf16x8*)&sVT[(dt * 16 + lr) * 232 + kc * 32 + lk * 8];
                acc = MFMA16(a, bb, acc);
            }
            unsigned short p[4];
#pragma unroll
            for (int i = 0; i < 4; i++) p[i] = f2bf(acc[i]);
            *(uint2*)&zdst[(size_t)(dt * 16 + lr) * 208 + mt * 16 + lk * 4] = *(uint2*)p;
        }
    }
}

// ===========================================================================
// MFMA chain, stage B — v4: register-prefetch pipeline (T14 async-stage).
// Round 9: 69.7 µs with staging latency exposed at every barrier (MfmaUtil
// 7%). Now: ZT(c+1)+KH1(c+1) issued into REGISTERS right after bar1
// (consumed next iteration); KH2(c) issued at iteration top (consumed after
// L1). ds_write reads regs at issue -> single-array reuse is WAR-safe.
// LDS layout, barriers, math, fragment mapping all unchanged from verified v3.
// ===========================================================================
__global__ __launch_bounds__(256, 2)
void yz_kernel(const unsigned short* __restrict__ QHb, const unsigned short* __restrict__ KHb,
               const unsigned short* __restrict__ Zt, const float* __restrict__ aflat,
               unsigned short* __restrict__ rect) {
    const int ns = blockIdx.x, h = blockIdx.y, b = blockIdx.z;
    const int n0 = ns * 49;
    const int t = threadIdx.x;
    const int w = t >> 6, l = t & 63;
    const int lr = l & 15, lk = l >> 4;

    __shared__ unsigned short sKH[112 * 72];   // 16,128 B (KH m-half)
    __shared__ unsigned short sZT[64 * 232];   // 29,696 B
    __shared__ unsigned short sL[64 * 232];    // 29,696 B -> total 75,520 B

    for (int e = t; e < 64 * 24; e += 256) {
        sZT[(e / 24) * 232 + 208 + (e % 24)] = 0;
        sL [(e / 24) * 232 + 208 + (e % 24)] = 0;
    }

    bf16x8 qf[2];
    {
        const int rel = w * 16 + lr;
        if (rel < 49) {
            const unsigned short* qsrc = QHb + (size_t)(b * 196 + n0 + rel) * 1152 + h * 64;
            qf[0] = *(const bf16x8*)(qsrc + lk * 8);
            qf[1] = *(const bf16x8*)(qsrc + 32 + lk * 8);
        } else {
            qf[0] = (bf16x8){0, 0, 0, 0, 0, 0, 0, 0};
            qf[1] = (bf16x8){0, 0, 0, 0, 0, 0, 0, 0};
        }
    }

    const size_t zbase = (((size_t)(b * 6 + h)) * 10) * 64 * 208;

    // prefetch register containers (static-indexed only — rule #20)
    uint4 zt_r[7], kh1_r[4], kh2_r[3];

    // prologue: prefetch c=0 (exposed once)
    {
        const unsigned short* zsrc = Zt + zbase;   // c = 0
#pragma unroll
        for (int i = 0; i < 7; i++) {
            const int e = t + i * 256;
            if (e < 1664) { const int d = e / 26, mc = e % 26;
                zt_r[i] = *(const uint4*)(zsrc + (size_t)d * 208 + mc * 8); }
        }
#pragma unroll
        for (int i = 0; i < 4; i++) {
            const int e = t + i * 256;
            if (e < 896) { const int r = e >> 3, ch = e & 7;
                kh1_r[i] = *(const uint4*)(KHb + (size_t)r * 768 + h * 64 + ch * 8); }
        }
    }

    f32x4 y[4];
#pragma unroll
    for (int i = 0; i < 4; i++) y[i] = (f32x4){0.f, 0.f, 0.f, 0.f};
    __syncthreads();   // pad zeros visible

    for (int c = 0; c < 10; c++) {
        // A: write prefetched ZT(c)+KH1(c) regs -> LDS; issue KH2(c) loads
#pragma unroll
        for (int i = 0; i < 7; i++) {
            const int e = t + i * 256;
            if (e < 1664) { const int d = e / 26, mc = e % 26;
                *(uint4*)&sZT[d * 232 + mc * 8] = zt_r[i]; }
        }
#pragma unroll
        for (int i = 0; i < 4; i++) {
            const int e = t + i * 256;
            if (e < 896) { const int r = e >> 3, ch = e & 7;
                *(uint4*)&sKH[r * 72 + ch * 8] = kh1_r[i]; }
        }
#pragma unroll
        for (int i = 0; i < 3; i++) {
            const int e = t + i * 256;
            const int r = e >> 3, ch = e & 7;
            kh2_r[i] = (112 + r < 196)
                ? *(const uint4*)(KHb + (size_t)(c * 196 + 112 + r) * 768 + h * 64 + ch * 8)
                : make_uint4(0, 0, 0, 0);
        }
        const float wc = aflat[b * 60 + h * 10 + c];
        __syncthreads();                       // bar1: staging visible
        // issue next-iter ZT/KH1 prefetch (hidden under L1+L2+PV compute)
        if (c < 9) {
            const unsigned short* zsrc = Zt + zbase + (size_t)(c + 1) * 64 * 208;
#pragma unroll
            for (int i = 0; i < 7; i++) {
                const int e = t + i * 256;
                if (e < 1664) { const int d = e / 26, mc = e % 26;
                    zt_r[i] = *(const uint4*)(zsrc + (size_t)d * 208 + mc * 8); }
            }
#pragma unroll
            for (int i = 0; i < 4; i++) {
                const int e = t + i * 256;
                if (e < 896) { const int r = e >> 3, ch = e & 7;
                    kh1_r[i] = *(const uint4*)(KHb + (size_t)((c + 1) * 196 + r) * 768 + h * 64 + ch * 8); }
            }
        }
        // B: L half1 (mt 0..6) -> wave-local sL rows
#pragma unroll
        for (int mt = 0; mt < 7; mt++) {
            f32x4 acc = {0.f, 0.f, 0.f, 0.f};
            bf16x8 b0 = *(const bf16x8*)&sKH[(mt * 16 + lr) * 72 + lk * 8];
            acc = MFMA16(qf[0], b0, acc);
            bf16x8 b1 = *(const bf16x8*)&sKH[(mt * 16 + lr) * 72 + 32 + lk * 8];
            acc = MFMA16(qf[1], b1, acc);
            const int lrow = w * 16 + lk * 4, lcol = mt * 16 + lr;
#pragma unroll
            for (int i = 0; i < 4; i++)
                sL[(lrow + i) * 232 + lcol] = f2bf(wc * fmaxf(0.f, -SCL * acc[i]));
        }
        __syncthreads();                       // bar2: all waves done with KH half1
        // C: write KH2(c) regs -> LDS
#pragma unroll
        for (int i = 0; i < 3; i++) {
            const int e = t + i * 256;
            const int r = e >> 3, ch = e & 7;
            *(uint4*)&sKH[r * 72 + ch * 8] = kh2_r[i];
        }
        __syncthreads();                       // bar3
        // D: L half2 (mt 7..12)
#pragma unroll
        for (int mt = 7; mt < 13; mt++) {
            f32x4 acc = {0.f, 0.f, 0.f, 0.f};
            bf16x8 b0 = *(const bf16x8*)&sKH[((mt - 7) * 16 + lr) * 72 + lk * 8];
            acc = MFMA16(qf[0], b0, acc);
            bf16x8 b1 = *(const bf16x8*)&sKH[((mt - 7) * 16 + lr) * 72 + 32 + lk * 8];
            acc = MFMA16(qf[1], b1, acc);
            const int lrow = w * 16 + lk * 4, lcol = mt * 16 + lr;
#pragma unroll
            for (int i = 0; i < 4; i++)
                sL[(lrow + i) * 232 + lcol] = f2bf(wc * fmaxf(0.f, -SCL * acc[i]));
        }
        // E: PV (sL rows wave-local; sZT stable since bar1)
#pragma unroll
        for (int dt = 0; dt < 4; dt++) {
            f32x4 acc = y[dt];
#pragma unroll
            for (int mc = 0; mc < 7; mc++) {
                bf16x8 a  = *(const bf16x8*)&sL[(w * 16 + lr) * 232 + mc * 32 + lk * 8];
                bf16x8 bb = *(const bf16x8*)&sZT[(dt * 16 + lr) * 232 + mc * 32 + lk * 8];
                acc = MFMA16(a, bb, acc);
            }
            y[dt] = acc;
        }
        __syncthreads();                       // bar4: sZT/sKH free for next c
    }

#pragma unroll
    for (int dt = 0; dt < 4; dt++)
#pragma unroll
        for (int i = 0; i < 4; i++) {
            const int rel = w * 16 + lk * 4 + i;
            if (rel < 49)
                rect[(((size_t)(b * 6 + h)) * 196 + n0 + rel) * 64 + dt * 16 + lr] = f2bf(y[dt][i]);
        }
}

// ---------------------------------------------------------------------------
// Copy anchors verbatim.
// ---------------------------------------------------------------------------
__global__ void copy_anchors(const float* __restrict__ x, float* __restrict__ out) {
    const int e = blockIdx.x * 256 + threadIdx.x;
    if (e < 189120) {
        const int base = 16 * 197 * 384 / 4;
        ((float4*)out)[base + e] = ((const float4*)x)[base + e];
    }
}

// ---------------------------------------------------------------------------
// kernel_launch. Workspace in f32 units, total 12,655,296 f = 50.6 MB.
// Layout: Px | Pa | rect | xx | Wx_t | Wr_t | W1_t | W2_t | Zt (hdn/G alias
// Zt, dead after yz). No overlaps among live ranges.
// ---------------------------------------------------------------------------
extern "C" void kernel_launch(void* const* d_in, const int* in_sizes, int n_in,
                              void* d_out, int out_size, void* d_ws, size_t ws_size,
                              hipStream_t stream) {
    (void)in_sizes; (void)n_in; (void)out_size; (void)ws_size;
    const float* x       = (const float*)d_in[0];
    const float* Wqv     = (const float*)d_in[1];
    const float* Wk      = (const float*)d_in[2];
    const float* Wq_proj = (const float*)d_in[3];
    const float* bq_proj = (const float*)d_in[4];
    const float* Wqk     = (const float*)d_in[5];
    const float* Wqk2    = (const float*)d_in[6];
    const float* Wv      = (const float*)d_in[7];
    const float* Wr_proj = (const float*)d_in[8];
    const float* br_proj = (const float*)d_in[9];
    const float* g1      = (const float*)d_in[10];
    const float* b1      = (const float*)d_in[11];
    const float* g2      = (const float*)d_in[12];
    const float* b2      = (const float*)d_in[13];
    const float* g3      = (const float*)d_in[14];
    const float* b3      = (const float*)d_in[15];
    const float* W1      = (const float*)d_in[16];
    const float* bm1     = (const float*)d_in[17];
    const float* W2      = (const float*)d_in[18];
    const float* bm2     = (const float*)d_in[19];

    float* ws = (float*)d_ws;
    float* n1      = ws;                                       //      9,984
    float* qv      = ws + 9984;                                //      7,680
    float* kcls    = ws + 17664;                               //      6,144
    float* aflat   = ws + 23808;                               //        960
    float* cls_pre = ws + 24768;                               //      6,144
    unsigned short* n2x_bf  = (unsigned short*)(ws + 30912);   // 3136x384 bf16  [ends   633,024]
    unsigned short* n2a_bf  = (unsigned short*)(ws + 633024);  // 1960x384 bf16  [ends 1,009,344]
    unsigned short* Px      = (unsigned short*)(ws + 1009344); // 3136x1152 bf16 [ends 2,815,680]
    unsigned short* Pa      = (unsigned short*)(ws + 2815680); // 1960x768 bf16  [ends 3,568,320]
    unsigned short* rect_bf = (unsigned short*)(ws + 3568320); // 3136x384 bf16  [ends 4,170,432]
    float* xx               = ws + 4170432;                    // 16x197x384 f32 [ends 5,380,800]
    unsigned short* Wx_t    = (unsigned short*)(ws + 5380800); // 1152x384 bf16  [ends 5,601,984]
    unsigned short* Wr_t    = (unsigned short*)(ws + 5601984); // 384x384 bf16   [ends 5,675,712]
    unsigned short* W1_t    = (unsigned short*)(ws + 5675712); // 1536x384 bf16  [ends 5,970,624]
    unsigned short* W2_t    = (unsigned short*)(ws + 5970624); // 384x1536 bf16  [ends 6,265,536]
    unsigned short* Zt      = (unsigned short*)(ws + 6265536); // 96*10*64*208   [ends 12,655,296]
    unsigned short* hdn_bf  = (unsigned short*)(ws + 6265536); // alias Zt (dead after yz)
    unsigned short* G_bf    = (unsigned short*)(ws + 6870720); // alias Zt region
    float* outf = (float*)d_out;

    // column-slice views of the fused projection buffers
    unsigned short* QHb = Px;           // stride 1152
    unsigned short* Q2b = Px + 384;
    unsigned short* VRb = Px + 768;
    unsigned short* KHb = Pa;           // stride 768
    unsigned short* K2b = Pa + 384;

    // 0. all weight transpose-casts in one launch
    wcast_all<<<432, 256, 0, stream>>>(Wqk, Wqk2, Wv, Wr_proj, W1, W2,
                                       Wx_t, Wr_t, W1_t, W2_t);
    // 1. all LayerNorms (cls fp32 + image bf16) in one launch
    ln_all<<<5122, 64, 0, stream>>>(x, n1, n2x_bf, g1, b1, g2, b2);
    // 2. qv / kcls (latency-optimized cls GEMMs)
    gemm_cls<10><<<12, 256, 0, stream>>>(n1 + 16 * 384, Wqv, nullptr, qv, 768, 768);
    gemm_cls<16><<<6, 256, 0, stream>>>(n1, Wk, nullptr, kcls, 384, 384);
    // 3. cls attention
    attn_cls_kernel<<<16, 64, 0, stream>>>(qv, kcls, aflat, cls_pre);
    // 4. fused head projections: Px = n2x @ [Wqk|Wqk2|Wv]; Pa = n2a @ [Wqk|Wqk2]
    gemm_mfma<0><<<dim3(9, 49), 256, 0, stream>>>(n2x_bf, Wx_t, nullptr, nullptr, Px, 3136, 1152, 384);
    gemm_mfma<0><<<dim3(6, 31), 256, 0, stream>>>(n2a_bf, Wx_t, nullptr, nullptr, Pa, 1960, 768, 384);
    // 5. chain stage A (fused per-wave S->R->Z)
    rz_kernel<<<dim3(10, 6, 16), 256, 0, stream>>>(Q2b, K2b, VRb, Zt, 1152, 768, 1152);
    // 6. chain stage B -> rect bf16 (reshape layout), register-prefetch pipeline
    yz_kernel<<<dim3(4, 6, 16), 256, 0, stream>>>(QHb, KHb, Zt, aflat, rect_bf);
    // 7. cls_out -> xx token 0
    gemm_cls<16><<<6, 256, 0, stream>>>(cls_pre, Wq_proj, bq_proj, xx, 384, 197 * 384);
    // 8. xx[:,1:] = rect @ Wr_proj + br + x_im  (remapped rows)
    gemm_mfma<1><<<dim3(3, 49), 256, 0, stream>>>(rect_bf, Wr_t, br_proj, x, xx, 3136, 384, 384);
    // 9. LN3 (bf16 out into hdn)
    ln3_kernel<<<3152, 64, 0, stream>>>(xx, hdn_bf, g3, b3);
    // 10. MLP up + GELU -> bf16 G
    gemm_mfma<2><<<dim3(12, 50), 256, 0, stream>>>(hdn_bf, W1_t, bm1, nullptr, G_bf, 3152, 1536, 384);
    // 11. MLP down + bias + residual -> out rows 0..3151
    gemm_mfma<3><<<dim3(3, 50), 256, 0, stream>>>(G_bf, W2_t, bm2, xx, outf, 3152, 384, 1536);
    // 12. anchors pass-through
    copy_anchors<<<739, 256, 0, stream>>>(x, outf);
}

// Round 12
// 433.793 us; speedup vs baseline: 1.1331x; 1.1331x over previous
//
#include <hip/hip_runtime.h>
#include <hip/hip_bf16.h>
#include <math.h>

#define SCL 0.125f

typedef float f32x4 __attribute__((ext_vector_type(4)));
typedef short bf16x8 __attribute__((ext_vector_type(8)));   // 8 bf16 in 4 VGPRs
#define MFMA16(a, b, c) __builtin_amdgcn_mfma_f32_16x16x32_bf16((a), (b), (c), 0, 0, 0)

// f32 -> bf16 round-to-nearest-even
__device__ __forceinline__ unsigned short f2bf(float f) {
    unsigned int u = __builtin_bit_cast(unsigned int, f);
    u = (u + 0x7FFFu + ((u >> 16) & 1u)) >> 16;
    return (unsigned short)u;
}

__device__ __forceinline__ float gelu_exact(float v) {
    return 0.5f * v * (1.f + erff(v * 0.70710678118654752f));
}

// ---------------------------------------------------------------------------
// Fused LayerNorm: row 0..25 = cls tokens (g1/b1, fp32 -> n1),
// row 26..5121 = image tokens (g2/b2, bf16 -> n2_bf; first 3136 xs, rest anchors).
// ---------------------------------------------------------------------------
__global__ void ln_all(const float* __restrict__ x, float* __restrict__ n1,
                       unsigned short* __restrict__ n2_bf,
                       const float* __restrict__ g1, const float* __restrict__ b1,
                       const float* __restrict__ g2, const float* __restrict__ b2) {
    const int row = blockIdx.x;
    const int lane = threadIdx.x;
    const float* src;
    const float *g, *bt;
    if (row < 26) {
        src = x + (size_t)row * (197 * 384);
        g = g1; bt = b1;
    } else {
        const int rr = row - 26;
        if (rr < 3136) { int b = rr / 196, n = rr % 196; src = x + (size_t)(b * 197 + 1 + n) * 384; }
        else { int r2 = rr - 3136; int b = r2 / 196, n = r2 % 196; src = x + (size_t)((16 + b) * 197 + 1 + n) * 384; }
        g = g2; bt = b2;
    }

    float v[6];
    float s = 0.f, s2 = 0.f;
#pragma unroll
    for (int j = 0; j < 6; j++) {
        v[j] = src[lane + j * 64];
        s += v[j];
        s2 += v[j] * v[j];
    }
#pragma unroll
    for (int o = 32; o; o >>= 1) {
        s  += __shfl_xor(s, o);
        s2 += __shfl_xor(s2, o);
    }
    const float mu = s * (1.f / 384.f);
    const float var = s2 * (1.f / 384.f) - mu * mu;
    const float rs = 1.f / sqrtf(var + 1e-5f);
#pragma unroll
    for (int j = 0; j < 6; j++) {
        const int c = lane + j * 64;
        const float r = (v[j] - mu) * rs * g[c] + bt[c];
        if (row < 26) n1[(size_t)row * 384 + c] = r;
        else          n2_bf[(size_t)(row - 26) * 384 + c] = f2bf(r);
    }
}

// ---------------------------------------------------------------------------
// LN3 (plain contiguous rows, bf16 out) — used for hdn.
// ---------------------------------------------------------------------------
__global__ void ln3_kernel(const float* __restrict__ x, unsigned short* __restrict__ outp,
                           const float* __restrict__ g, const float* __restrict__ bt) {
    const int row = blockIdx.x;
    const int lane = threadIdx.x;
    const float* src = x + (size_t)row * 384;
    float v[6];
    float s = 0.f, s2 = 0.f;
#pragma unroll
    for (int j = 0; j < 6; j++) {
        v[j] = src[lane + j * 64];
        s += v[j];
        s2 += v[j] * v[j];
    }
#pragma unroll
    for (int o = 32; o; o >>= 1) {
        s  += __shfl_xor(s, o);
        s2 += __shfl_xor(s2, o);
    }
    const float mu = s * (1.f / 384.f);
    const float var = s2 * (1.f / 384.f) - mu * mu;
    const float rs = 1.f / sqrtf(var + 1e-5f);
#pragma unroll
    for (int j = 0; j < 6; j++) {
        const int c = lane + j * 64;
        outp[(size_t)row * 384 + c] = f2bf((v[j] - mu) * rs * g[c] + bt[c]);
    }
}

// ---------------------------------------------------------------------------
// cls-path GEMM, latency-optimized.
// ---------------------------------------------------------------------------
template <int M>
__global__ void gemm_cls(const float* __restrict__ A, const float* __restrict__ B,
                         const float* __restrict__ bias, float* __restrict__ C,
                         int N, int ldc) {
    __shared__ float sA[M * 384];
    __shared__ float red[4][M][64];
    const int t = threadIdx.x;
    const int tc = t & 63, ks = t >> 6;
    const int n = blockIdx.x * 64 + tc;
    for (int e = t; e < M * 384; e += 256) sA[e] = A[e];
    __syncthreads();
    float acc[M];
#pragma unroll
    for (int m = 0; m < M; m++) acc[m] = 0.f;
    const int k0 = ks * 96;
#pragma unroll 4
    for (int k = k0; k < k0 + 96; k++) {
        const float bv = B[(size_t)k * N + n];
#pragma unroll
        for (int m = 0; m < M; m++) acc[m] += sA[m * 384 + k] * bv;
    }
#pragma unroll
    for (int m = 0; m < M; m++) red[ks][m][tc] = acc[m];
    __syncthreads();
    if (ks == 0) {
#pragma unroll
        for (int m = 0; m < M; m++) {
            float s = red[0][m][tc] + red[1][m][tc] + red[2][m][tc] + red[3][m][tc];
            if (bias) s += bias[n];
            C[(size_t)m * ldc + n] = s;
        }
    }
}

// ---------------------------------------------------------------------------
// cls attention (verified)
// ---------------------------------------------------------------------------
__global__ void attn_cls_kernel(const float* __restrict__ qv, const float* __restrict__ kcls,
                                float* __restrict__ aflat, float* __restrict__ cls_pre) {
    const int b = blockIdx.x;
    const int t = threadIdx.x;  // 64
    __shared__ float kb[384];
    __shared__ float pl[60];
#pragma unroll
    for (int j = 0; j < 6; j++) kb[t + j * 64] = kcls[b * 384 + t + j * 64];
    __syncthreads();
    if (t < 60) {
        const int n = t / 6, h = t % 6;
        float acc = 0.f;
        for (int d = 0; d < 64; d++) acc += qv[n * 768 + h * 64 + d] * kb[h * 64 + d];
        pl[t] = acc * SCL;
    }
    __syncthreads();
    if (t < 6) {
        float m = -1e30f;
        for (int n = 0; n < 10; n++) m = fmaxf(m, pl[n * 6 + t]);
        float p[10], sum = 0.f;
        for (int n = 0; n < 10; n++) { p[n] = expf(pl[n * 6 + t] - m); sum += p[n]; }
        const float inv = 1.f / sum;
        for (int n = 0; n < 10; n++) {
            const float pr = p[n] * inv;
            pl[n * 6 + t] = pr;
            aflat[b * 60 + n * 6 + t] = pr;   // reference flat (n,h) order
        }
    }
    __syncthreads();
#pragma unroll
    for (int j = 0; j < 6; j++) {
        const int c = t + j * 64;
        const int h = c >> 6;
        float acc = 0.f;
        for (int n = 0; n < 10; n++) acc += pl[n * 6 + h] * qv[n * 768 + 384 + c];
        cls_pre[b * 384 + c] = acc;
    }
}

// ---------------------------------------------------------------------------
// ALL weight transpose-casts in ONE launch.
// ---------------------------------------------------------------------------
__global__ void wcast_all(const float* __restrict__ Wqk, const float* __restrict__ Wqk2,
                          const float* __restrict__ Wv, const float* __restrict__ Wr,
                          const float* __restrict__ W1, const float* __restrict__ W2,
                          unsigned short* __restrict__ Wx_t, unsigned short* __restrict__ Wr_t,
                          unsigned short* __restrict__ W1_t, unsigned short* __restrict__ W2_t) {
    const int bid = blockIdx.x;
    const float* W; unsigned short* dst; int K, N, nx, ky;
    if (bid < 108) {
        const int z = bid / 36, rem = bid % 36;
        W = (z == 0) ? Wqk : (z == 1 ? Wqk2 : Wv);
        dst = Wx_t + (size_t)z * 384 * 384;
        K = 384; N = 384; nx = rem % 6; ky = rem / 6;
    } else if (bid < 144) {
        const int rem = bid - 108;
        W = Wr; dst = Wr_t; K = 384; N = 384; nx = rem % 6; ky = rem / 6;
    } else if (bid < 288) {
        const int rem = bid - 144;
        W = W1; dst = W1_t; K = 384; N = 1536; nx = rem % 24; ky = rem / 24;
    } else {
        const int rem = bid - 288;
        W = W2; dst = W2_t; K = 1536; N = 384; nx = rem % 6; ky = rem / 6;
    }
    const int n0 = nx * 64, k0 = ky * 64;
    __shared__ unsigned short sT[64][72];
    const int t = threadIdx.x;
    for (int e = t; e < 4096; e += 256) {
        const int k = e >> 6, n = e & 63;
        sT[n][k] = f2bf(W[(size_t)(k0 + k) * N + n0 + n]);
    }
    __syncthreads();
    for (int e = t; e < 512; e += 256) {
        const int n = e >> 3, ch = e & 7;
        *(uint4*)&dst[(size_t)(n0 + n) * K + k0 + ch * 8] = *(uint4*)&sT[n][ch * 8];
    }
}

// ---------------------------------------------------------------------------
// bf16 MFMA GEMM: C = epilogue(A @ Bt^T).
// EPI: 0 bf16-out plain; 1 fp32 +bias +res REMAP; 2 bf16 +bias +GELU;
//      3 fp32 +bias +res.
// ---------------------------------------------------------------------------
template <int EPI>
__launch_bounds__(256)
__global__ void gemm_mfma(const unsigned short* __restrict__ A,
                          const unsigned short* __restrict__ Bt,
                          const float* __restrict__ bias, const float* __restrict__ res,
                          void* __restrict__ Cout, int M, int N, int K) {
    const int m0 = blockIdx.y * 64, n0 = blockIdx.x * 128;
    const int t = threadIdx.x;
    const int w = t >> 6, l = t & 63;
    const int lr = l & 15, lk = l >> 4;
    const int wr = w >> 1, wc = w & 1;

    __shared__ unsigned short sA[64][72];
    __shared__ unsigned short sB[128][72];

    f32x4 acc[2][4];
#pragma unroll
    for (int mi = 0; mi < 2; mi++)
#pragma unroll
        for (int nj = 0; nj < 4; nj++) acc[mi][nj] = (f32x4){0.f, 0.f, 0.f, 0.f};

    for (int k0 = 0; k0 < K; k0 += 64) {
        for (int e = t; e < 512; e += 256) {
            const int r = e >> 3, ch = e & 7;
            uint4 v = make_uint4(0, 0, 0, 0);
            const int row = m0 + r;
            if (row < M) v = *(const uint4*)(A + (size_t)row * K + k0 + ch * 8);
            *(uint4*)&sA[r][ch * 8] = v;
        }
        for (int e = t; e < 1024; e += 256) {
            const int r = e >> 3, ch = e & 7;
            *(uint4*)&sB[r][ch * 8] = *(const uint4*)(Bt + (size_t)(n0 + r) * K + k0 + ch * 8);
        }
        __syncthreads();
#pragma unroll
        for (int kc = 0; kc < 2; kc++) {
            bf16x8 af[2], bfr[4];
#pragma unroll
            for (int mi = 0; mi < 2; mi++)
                af[mi] = *(const bf16x8*)&sA[wr * 32 + mi * 16 + lr][kc * 32 + lk * 8];
#pragma unroll
            for (int nj = 0; nj < 4; nj++)
                bfr[nj] = *(const bf16x8*)&sB[wc * 64 + nj * 16 + lr][kc * 32 + lk * 8];
#pragma unroll
            for (int mi = 0; mi < 2; mi++)
#pragma unroll
                for (int nj = 0; nj < 4; nj++)
                    acc[mi][nj] = MFMA16(af[mi], bfr[nj], acc[mi][nj]);
        }
        __syncthreads();
    }

#pragma unroll
    for (int mi = 0; mi < 2; mi++)
#pragma unroll
        for (int nj = 0; nj < 4; nj++) {
            const int col = n0 + wc * 64 + nj * 16 + lr;
#pragma unroll
            for (int i = 0; i < 4; i++) {
                const int row = m0 + wr * 32 + mi * 16 + lk * 4 + i;
                if (row >= M) continue;
                float v = acc[mi][nj][i];
                if (EPI == 0) {
                    ((unsigned short*)Cout)[(size_t)row * N + col] = f2bf(v);
                } else if (EPI == 1) {
                    const int crow = row + row / 196 + 1;
                    v += bias[col] + res[(size_t)crow * N + col];
                    ((float*)Cout)[(size_t)crow * N + col] = v;
                } else if (EPI == 2) {
                    ((unsigned short*)Cout)[(size_t)row * N + col] = f2bf(gelu_exact(v + bias[col]));
                } else {
                    v += bias[col] + res[(size_t)row * N + col];
                    ((float*)Cout)[(size_t)row * N + col] = v;
                }
            }
        }
}

// ===========================================================================
// MFMA chain, stage A — v2 (round 9 verified: 2 blocks/CU, fused S->R->Z).
// ===========================================================================
__global__ __launch_bounds__(256, 2)
void rz_kernel(const unsigned short* __restrict__ Q2b, const unsigned short* __restrict__ K2b,
               const unsigned short* __restrict__ VRb, unsigned short* __restrict__ Zt,
               int sq, int sk, int sv) {
    const int c = blockIdx.x, h = blockIdx.y, b = blockIdx.z;
    const int t = threadIdx.x;
    const int w = t >> 6, l = t & 63;
    const int lr = l & 15, lk = l >> 4;

    __shared__ unsigned short sVT[64 * 232];        // vr^T [d][k], 29,696 B
    __shared__ unsigned short sR[4 * 16 * 232];     // per-wave R tile, 29,696 B
    unsigned short* sRw = sR + w * (16 * 232);

    const unsigned short* vrsrc = VRb + (size_t)(b * 196) * sv + h * 64;
    for (int e = t; e < 196 * 8; e += 256) {
        const int kk = e >> 3, ch = e & 7;
        uint4 v = *(const uint4*)(vrsrc + (size_t)kk * sv + ch * 8);
        unsigned short vs[8]; *(uint4*)vs = v;
#pragma unroll
        for (int j = 0; j < 8; j++) sVT[(ch * 8 + j) * 232 + kk] = vs[j];
    }
    for (int e = t; e < 64 * 36; e += 256) sVT[(e / 36) * 232 + 196 + (e % 36)] = 0;
    for (int e = l; e < 16 * 24; e += 64) sRw[(e / 24) * 232 + 208 + (e % 24)] = 0;

    bf16x8 qf0[13], qf1[13];
    const unsigned short* q2src = Q2b + (size_t)(b * 196) * sq + h * 64;
#pragma unroll
    for (int kt = 0; kt < 13; kt++) {
        const int r = kt * 16 + lr;
        if (r < 196) {
            const unsigned short* p = q2src + (size_t)r * sq;
            qf0[kt] = *(const bf16x8*)(p + lk * 8);
            qf1[kt] = *(const bf16x8*)(p + 32 + lk * 8);
        } else {
            qf0[kt] = (bf16x8){0, 0, 0, 0, 0, 0, 0, 0};
            qf1[kt] = (bf16x8){0, 0, 0, 0, 0, 0, 0, 0};
        }
    }
    __syncthreads();

    const unsigned short* k2src = K2b + (size_t)(c * 196) * sk + h * 64;
    unsigned short* zdst = Zt + ((((size_t)(b * 6 + h)) * 10 + c) * 64) * 208;

    for (int mt = w; mt < 13; mt += 4) {
        bf16x8 a0, a1;
        const int ar = mt * 16 + lr;
        if (ar < 196) {
            const unsigned short* p = k2src + (size_t)ar * sk;
            a0 = *(const bf16x8*)(p + lk * 8);
            a1 = *(const bf16x8*)(p + 32 + lk * 8);
        } else {
            a0 = (bf16x8){0, 0, 0, 0, 0, 0, 0, 0};
            a1 = (bf16x8){0, 0, 0, 0, 0, 0, 0, 0};
        }
#pragma unroll
        for (int kt = 0; kt < 13; kt++) {
            f32x4 acc = {0.f, 0.f, 0.f, 0.f};
            acc = MFMA16(a0, qf0[kt], acc);
            acc = MFMA16(a1, qf1[kt], acc);
#pragma unroll
            for (int i = 0; i < 4; i++)
                sRw[(lk * 4 + i) * 232 + kt * 16 + lr] = f2bf(fmaxf(0.f, SCL * acc[i]));
        }
#pragma unroll
        for (int dt = 0; dt < 4; dt++) {
            f32x4 acc = {0.f, 0.f, 0.f, 0.f};
#pragma unroll
            for (int kc = 0; kc < 7; kc++) {
                bf16x8 a  = *(const bf16x8*)&sRw[lr * 232 + kc * 32 + lk * 8];
                bf16x8 bb = *(const bf16x8*)&sVT[(dt * 16 + lr) * 232 + kc * 32 + lk * 8];
                acc = MFMA16(a, bb, acc);
            }
            unsigned short p[4];
#pragma unroll
            for (int i = 0; i < 4; i++) p[i] = f2bf(acc[i]);
            *(uint2*)&zdst[(size_t)(dt * 16 + lr) * 208 + mt * 16 + lk * 4] = *(uint2*)p;
        }
    }
}

// ===========================================================================
// MFMA chain, stage B — v5: register-prefetch with NAMED uint4 variables.
// Round 11 post-mortem: v4's uint4 ARRAYS were demoted to scratch
// (VGPR_Count stayed 88, WRITE_SIZE 2.4 -> 134 MB = spill traffic,
// yz 69.7 -> 98 µs). Rule #20 fix: hand-unrolled named registers
// (z0..z6, ka0..ka3, kb0..kb2) with compile-time tail guards
// (z6/ka3: t<128; kb2: t<160). Structure/barriers identical to verified v3/v4.
// ===========================================================================
#define ZT_LD(dst, e_, src) { const int _e = (e_); const int _d = _e / 26, _mc = _e % 26; \
    dst = *(const uint4*)((src) + (size_t)_d * 208 + _mc * 8); }
#define ZT_ST(val, e_) { const int _e = (e_); const int _d = _e / 26, _mc = _e % 26; \
    *(uint4*)&sZT[_d * 232 + _mc * 8] = (val); }
#define KH_LD(dst, e_, rowbase) { const int _e = (e_); const int _r = _e >> 3, _ch = _e & 7; \
    dst = *(const uint4*)(KHb + (size_t)((rowbase) + _r) * 768 + h * 64 + _ch * 8); }
#define KH_ST(val, e_) { const int _e = (e_); const int _r = _e >> 3, _ch = _e & 7; \
    *(uint4*)&sKH[_r * 72 + _ch * 8] = (val); }

__global__ __launch_bounds__(256, 2)
void yz_kernel(const unsigned short* __restrict__ QHb, const unsigned short* __restrict__ KHb,
               const unsigned short* __restrict__ Zt, const float* __restrict__ aflat,
               unsigned short* __restrict__ rect) {
    const int ns = blockIdx.x, h = blockIdx.y, b = blockIdx.z;
    const int n0 = ns * 49;
    const int t = threadIdx.x;
    const int w = t >> 6, l = t & 63;
    const int lr = l & 15, lk = l >> 4;

    __shared__ unsigned short sKH[112 * 72];   // 16,128 B (KH m-half)
    __shared__ unsigned short sZT[64 * 232];   // 29,696 B
    __shared__ unsigned short sL[64 * 232];    // 29,696 B -> total 75,520 B

    for (int e = t; e < 64 * 24; e += 256) {
        sZT[(e / 24) * 232 + 208 + (e % 24)] = 0;
        sL [(e / 24) * 232 + 208 + (e % 24)] = 0;
    }

    bf16x8 qf[2];
    {
        const int rel = w * 16 + lr;
        if (rel < 49) {
            const unsigned short* qsrc = QHb + (size_t)(b * 196 + n0 + rel) * 1152 + h * 64;
            qf[0] = *(const bf16x8*)(qsrc + lk * 8);
            qf[1] = *(const bf16x8*)(qsrc + 32 + lk * 8);
        } else {
            qf[0] = (bf16x8){0, 0, 0, 0, 0, 0, 0, 0};
            qf[1] = (bf16x8){0, 0, 0, 0, 0, 0, 0, 0};
        }
    }

    const size_t zbase = (((size_t)(b * 6 + h)) * 10) * 64 * 208;

    // NAMED prefetch registers (rule #20: arrays spilled; named vars don't)
    uint4 z0, z1, z2, z3, z4, z5, z6;     // ZT tile: 1664 uint4 (tail 128)
    uint4 ka0, ka1, ka2, ka3;             // KH rows 0..111: 896 uint4 (tail 128)
    uint4 kb0, kb1, kb2;                  // KH rows 112..207: 768 uint4 (valid<672)

    // prologue: prefetch c=0 (exposed once)
    {
        const unsigned short* zsrc = Zt + zbase;
        ZT_LD(z0, t, zsrc); ZT_LD(z1, t + 256, zsrc); ZT_LD(z2, t + 512, zsrc);
        ZT_LD(z3, t + 768, zsrc); ZT_LD(z4, t + 1024, zsrc); ZT_LD(z5, t + 1280, zsrc);
        if (t < 128) { ZT_LD(z6, t + 1536, zsrc); } else z6 = make_uint4(0, 0, 0, 0);
        KH_LD(ka0, t, 0); KH_LD(ka1, t + 256, 0); KH_LD(ka2, t + 512, 0);
        if (t < 128) { KH_LD(ka3, t + 768, 0); } else ka3 = make_uint4(0, 0, 0, 0);
    }

    f32x4 y[4];
#pragma unroll
    for (int i = 0; i < 4; i++) y[i] = (f32x4){0.f, 0.f, 0.f, 0.f};
    __syncthreads();   // pad zeros visible

    for (int c = 0; c < 10; c++) {
        // A: write prefetched ZT(c)+KH1(c) regs -> LDS; issue KH2(c) loads
        ZT_ST(z0, t); ZT_ST(z1, t + 256); ZT_ST(z2, t + 512);
        ZT_ST(z3, t + 768); ZT_ST(z4, t + 1024); ZT_ST(z5, t + 1280);
        if (t < 128) { ZT_ST(z6, t + 1536); }
        KH_ST(ka0, t); KH_ST(ka1, t + 256); KH_ST(ka2, t + 512);
        if (t < 128) { KH_ST(ka3, t + 768); }
        KH_LD(kb0, t, c * 196 + 112);
        KH_LD(kb1, t + 256, c * 196 + 112);
        if (t < 160) { KH_LD(kb2, t + 512, c * 196 + 112); } else kb2 = make_uint4(0, 0, 0, 0);
        const float wc = aflat[b * 60 + h * 10 + c];
        __syncthreads();                       // bar1: staging visible
        // issue next-iter ZT/KH1 prefetch (hidden under L1+L2+PV compute)
        if (c < 9) {
            const unsigned short* zsrc = Zt + zbase + (size_t)(c + 1) * 64 * 208;
            ZT_LD(z0, t, zsrc); ZT_LD(z1, t + 256, zsrc); ZT_LD(z2, t + 512, zsrc);
            ZT_LD(z3, t + 768, zsrc); ZT_LD(z4, t + 1024, zsrc); ZT_LD(z5, t + 1280, zsrc);
            if (t < 128) { ZT_LD(z6, t + 1536, zsrc); }
            KH_LD(ka0, t, (c + 1) * 196); KH_LD(ka1, t + 256, (c + 1) * 196);
            KH_LD(ka2, t + 512, (c + 1) * 196);
            if (t < 128) { KH_LD(ka3, t + 768, (c + 1) * 196); }
        }
        // B: L half1 (mt 0..6) -> wave-local sL rows
#pragma unroll
        for (int mt = 0; mt < 7; mt++) {
            f32x4 acc = {0.f, 0.f, 0.f, 0.f};
            bf16x8 b0 = *(const bf16x8*)&sKH[(mt * 16 + lr) * 72 + lk * 8];
            acc = MFMA16(qf[0], b0, acc);
            bf16x8 b1 = *(const bf16x8*)&sKH[(mt * 16 + lr) * 72 + 32 + lk * 8];
            acc = MFMA16(qf[1], b1, acc);
            const int lrow = w * 16 + lk * 4, lcol = mt * 16 + lr;
#pragma unroll
            for (int i = 0; i < 4; i++)
                sL[(lrow + i) * 232 + lcol] = f2bf(wc * fmaxf(0.f, -SCL * acc[i]));
        }
        __syncthreads();                       // bar2: all waves done with KH half1
        // C: write KH2(c) regs -> LDS (rows >=196 are zeros via kb2 guard)
        KH_ST(kb0, t); KH_ST(kb1, t + 256); KH_ST(kb2, t + 512);
        __syncthreads();                       // bar3
        // D: L half2 (mt 7..12)
#pragma unroll
        for (int mt = 7; mt < 13; mt++) {
            f32x4 acc = {0.f, 0.f, 0.f, 0.f};
            bf16x8 b0 = *(const bf16x8*)&sKH[((mt - 7) * 16 + lr) * 72 + lk * 8];
            acc = MFMA16(qf[0], b0, acc);
            bf16x8 b1 = *(const bf16x8*)&sKH[((mt - 7) * 16 + lr) * 72 + 32 + lk * 8];
            acc = MFMA16(qf[1], b1, acc);
            const int lrow = w * 16 + lk * 4, lcol = mt * 16 + lr;
#pragma unroll
            for (int i = 0; i < 4; i++)
                sL[(lrow + i) * 232 + lcol] = f2bf(wc * fmaxf(0.f, -SCL * acc[i]));
        }
        // E: PV (sL rows wave-local; sZT stable since bar1)
#pragma unroll
        for (int dt = 0; dt < 4; dt++) {
            f32x4 acc = y[dt];
#pragma unroll
            for (int mc = 0; mc < 7; mc++) {
                bf16x8 a  = *(const bf16x8*)&sL[(w * 16 + lr) * 232 + mc * 32 + lk * 8];
                bf16x8 bb = *(const bf16x8*)&sZT[(dt * 16 + lr) * 232 + mc * 32 + lk * 8];
                acc = MFMA16(a, bb, acc);
            }
            y[dt] = acc;
        }
        __syncthreads();                       // bar4: sZT/sKH free for next c
    }

#pragma unroll
    for (int dt = 0; dt < 4; dt++)
#pragma unroll
        for (int i = 0; i < 4; i++) {
            const int rel = w * 16 + lk * 4 + i;
            if (rel < 49)
                rect[(((size_t)(b * 6 + h)) * 196 + n0 + rel) * 64 + dt * 16 + lr] = f2bf(y[dt][i]);
        }
}

// ---------------------------------------------------------------------------
// Copy anchors verbatim.
// ---------------------------------------------------------------------------
__global__ void copy_anchors(const float* __restrict__ x, float* __restrict__ out) {
    const int e = blockIdx.x * 256 + threadIdx.x;
    if (e < 189120) {
        const int base = 16 * 197 * 384 / 4;
        ((float4*)out)[base + e] = ((const float4*)x)[base + e];
    }
}

// ---------------------------------------------------------------------------
// kernel_launch. Workspace in f32 units, total 12,655,296 f = 50.6 MB.
// Layout: Px | Pa | rect | xx | Wx_t | Wr_t | W1_t | W2_t | Zt (hdn/G alias
// Zt, dead after yz). No overlaps among live ranges.
// ---------------------------------------------------------------------------
extern "C" void kernel_launch(void* const* d_in, const int* in_sizes, int n_in,
                              void* d_out, int out_size, void* d_ws, size_t ws_size,
                              hipStream_t stream) {
    (void)in_sizes; (void)n_in; (void)out_size; (void)ws_size;
    const float* x       = (const float*)d_in[0];
    const float* Wqv     = (const float*)d_in[1];
    const float* Wk      = (const float*)d_in[2];
    const float* Wq_proj = (const float*)d_in[3];
    const float* bq_proj = (const float*)d_in[4];
    const float* Wqk     = (const float*)d_in[5];
    const float* Wqk2    = (const float*)d_in[6];
    const float* Wv      = (const float*)d_in[7];
    const float* Wr_proj = (const float*)d_in[8];
    const float* br_proj = (const float*)d_in[9];
    const float* g1      = (const float*)d_in[10];
    const float* b1      = (const float*)d_in[11];
    const float* g2      = (const float*)d_in[12];
    const float* b2      = (const float*)d_in[13];
    const float* g3      = (const float*)d_in[14];
    const float* b3      = (const float*)d_in[15];
    const float* W1      = (const float*)d_in[16];
    const float* bm1     = (const float*)d_in[17];
    const float* W2      = (const float*)d_in[18];
    const float* bm2     = (const float*)d_in[19];

    float* ws = (float*)d_ws;
    float* n1      = ws;                                       //      9,984
    float* qv      = ws + 9984;                                //      7,680
    float* kcls    = ws + 17664;                               //      6,144
    float* aflat   = ws + 23808;                               //        960
    float* cls_pre = ws + 24768;                               //      6,144
    unsigned short* n2x_bf  = (unsigned short*)(ws + 30912);   // 3136x384 bf16  [ends   633,024]
    unsigned short* n2a_bf  = (unsigned short*)(ws + 633024);  // 1960x384 bf16  [ends 1,009,344]
    unsigned short* Px      = (unsigned short*)(ws + 1009344); // 3136x1152 bf16 [ends 2,815,680]
    unsigned short* Pa      = (unsigned short*)(ws + 2815680); // 1960x768 bf16  [ends 3,568,320]
    unsigned short* rect_bf = (unsigned short*)(ws + 3568320); // 3136x384 bf16  [ends 4,170,432]
    float* xx               = ws + 4170432;                    // 16x197x384 f32 [ends 5,380,800]
    unsigned short* Wx_t    = (unsigned short*)(ws + 5380800); // 1152x384 bf16  [ends 5,601,984]
    unsigned short* Wr_t    = (unsigned short*)(ws + 5601984); // 384x384 bf16   [ends 5,675,712]
    unsigned short* W1_t    = (unsigned short*)(ws + 5675712); // 1536x384 bf16  [ends 5,970,624]
    unsigned short* W2_t    = (unsigned short*)(ws + 5970624); // 384x1536 bf16  [ends 6,265,536]
    unsigned short* Zt      = (unsigned short*)(ws + 6265536); // 96*10*64*208   [ends 12,655,296]
    unsigned short* hdn_bf  = (unsigned short*)(ws + 6265536); // alias Zt (dead after yz)
    unsigned short* G_bf    = (unsigned short*)(ws + 6870720); // alias Zt region
    float* outf = (float*)d_out;

    // column-slice views of the fused projection buffers
    unsigned short* QHb = Px;           // stride 1152
    unsigned short* Q2b = Px + 384;
    unsigned short* VRb = Px + 768;
    unsigned short* KHb = Pa;           // stride 768
    unsigned short* K2b = Pa + 384;

    // 0. all weight transpose-casts in one launch
    wcast_all<<<432, 256, 0, stream>>>(Wqk, Wqk2, Wv, Wr_proj, W1, W2,
                                       Wx_t, Wr_t, W1_t, W2_t);
    // 1. all LayerNorms (cls fp32 + image bf16) in one launch
    ln_all<<<5122, 64, 0, stream>>>(x, n1, n2x_bf, g1, b1, g2, b2);
    // 2. qv / kcls (latency-optimized cls GEMMs)
    gemm_cls<10><<<12, 256, 0, stream>>>(n1 + 16 * 384, Wqv, nullptr, qv, 768, 768);
    gemm_cls<16><<<6, 256, 0, stream>>>(n1, Wk, nullptr, kcls, 384, 384);
    // 3. cls attention
    attn_cls_kernel<<<16, 64, 0, stream>>>(qv, kcls, aflat, cls_pre);
    // 4. fused head projections: Px = n2x @ [Wqk|Wqk2|Wv]; Pa = n2a @ [Wqk|Wqk2]
    gemm_mfma<0><<<dim3(9, 49), 256, 0, stream>>>(n2x_bf, Wx_t, nullptr, nullptr, Px, 3136, 1152, 384);
    gemm_mfma<0><<<dim3(6, 31), 256, 0, stream>>>(n2a_bf, Wx_t, nullptr, nullptr, Pa, 1960, 768, 384);
    // 5. chain stage A (fused per-wave S->R->Z)
    rz_kernel<<<dim3(10, 6, 16), 256, 0, stream>>>(Q2b, K2b, VRb, Zt, 1152, 768, 1152);
    // 6. chain stage B -> rect bf16 (reshape layout), named-register prefetch
    yz_kernel<<<dim3(4, 6, 16), 256, 0, stream>>>(QHb, KHb, Zt, aflat, rect_bf);
    // 7. cls_out -> xx token 0
    gemm_cls<16><<<6, 256, 0, stream>>>(cls_pre, Wq_proj, bq_proj, xx, 384, 197 * 384);
    // 8. xx[:,1:] = rect @ Wr_proj + br + x_im  (remapped rows)
    gemm_mfma<1><<<dim3(3, 49), 256, 0, stream>>>(rect_bf, Wr_t, br_proj, x, xx, 3136, 384, 384);
    // 9. LN3 (bf16 out into hdn)
    ln3_kernel<<<3152, 64, 0, stream>>>(xx, hdn_bf, g3, b3);
    // 10. MLP up + GELU -> bf16 G
    gemm_mfma<2><<<dim3(12, 50), 256, 0, stream>>>(hdn_bf, W1_t, bm1, nullptr, G_bf, 3152, 1536, 384);
    // 11. MLP down + bias + residual -> out rows 0..3151
    gemm_mfma<3><<<dim3(3, 50), 256, 0, stream>>>(G_bf, W2_t, bm2, xx, outf, 3152, 384, 1536);
    // 12. anchors pass-through
    copy_anchors<<<739, 256, 0, stream>>>(x, outf);
}